// Round 7
// baseline (211.973 us; speedup 1.0000x reference)
//
#include <hip/hip_runtime.h>
#include <cstdint>
#include <math.h>

// Problem constants
#define D_MODEL 1024
#define N_HEADS 16
#define HEAD_DIM 64
#define BB 2
#define TT 2048
// Inputs fp32, OUTPUT fp32. Internal: bf16 MFMA GEMMs + bf16 MFMA flash attention.
// Q pre-scaled by (1/32)*log2(e) so softmax uses exp2 (v_exp_f32).
#define QSCALE 0.04508422002778011f
// Static softmax shift: logits tiny; shift folded into QK acc init.
#define MSTATIC 12.0f

typedef float f32x4 __attribute__((ext_vector_type(4)));
typedef float f32x16 __attribute__((ext_vector_type(16)));
typedef __bf16 bf16x8 __attribute__((ext_vector_type(8)));
typedef unsigned int u32x4 __attribute__((ext_vector_type(4)));

__device__ inline ushort f2bf(float f) {
    union { float f; uint32_t u; } c; c.f = f;
    uint32_t u = c.u;
    uint32_t r = (u + 0x7FFFu + ((u >> 16) & 1u)) >> 16;  // RNE
    return (ushort)r;
}
__device__ inline ushort f2bf_hw(float f) {
    __bf16 h = (__bf16)f;
    return __builtin_bit_cast(ushort, h);
}
// v_permlane32_swap_b32: after the op,
//   x'[l>=32] = y_old[l-32] (x keeps its lower half),
//   y'[l<32]  = x_old[l+32] (y keeps its upper half).
__device__ inline void pl32swap(unsigned int& x, unsigned int& y) {
    asm volatile("v_permlane32_swap_b32 %0, %1" : "+v"(x), "+v"(y));
}

// async global->LDS, 16B per lane; LDS dest = uniform base + lane*16B (m97/m104)
__device__ inline void load_lds16(const ushort* g, ushort* lds_uniform_base) {
    __builtin_amdgcn_global_load_lds(
        (const __attribute__((address_space(1))) uint32_t*)g,
        (__attribute__((address_space(3))) uint32_t*)lds_uniform_base, 16, 0, 0);
}

// ---------------- fused prep: conv_x + Wqkv^T + Wo^T (one launch) ----------
__global__ __launch_bounds__(256) void prep(
    const float4* __restrict__ xin, ushort4* __restrict__ xb,
    const float* __restrict__ Wqkv, ushort* __restrict__ WqkvT,
    const float* __restrict__ Wo, ushort* __restrict__ WoT)
{
    int bid = blockIdx.x;
    int tid = threadIdx.x;
    if (bid < 4096) {
        int i = bid * 256 + tid;
        float4 v = xin[i];
        ushort4 u;
        u.x = f2bf(v.x); u.y = f2bf(v.y); u.z = f2bf(v.z); u.w = f2bf(v.w);
        xb[i] = u;
        return;
    }
    __shared__ ushort tile[32][33];
    int tx = tid & 31, ty = tid >> 5;
    const float* in; ushort* out; int R, C, c0, r0;
    if (bid < 7168) {
        int b2 = bid - 4096;
        in = Wqkv; out = WqkvT; R = D_MODEL; C = 3 * D_MODEL;
        c0 = (b2 % 96) * 32; r0 = (b2 / 96) * 32;
    } else {
        int b3 = bid - 7168;
        in = Wo; out = WoT; R = D_MODEL; C = D_MODEL;
        c0 = (b3 % 32) * 32; r0 = (b3 / 32) * 32;
    }
#pragma unroll
    for (int i = 0; i < 32; i += 8)
        tile[ty + i][tx] = f2bf(in[(size_t)(r0 + ty + i) * C + (c0 + tx)]);
    __syncthreads();
#pragma unroll
    for (int i = 0; i < 32; i += 8)
        out[(size_t)(c0 + ty + i) * R + (r0 + tx)] = tile[tx][ty + i];
}

// --------- V [bh][t][64] bf16 -> VT [bh][64][t] bf16 ------------------------
__global__ __launch_bounds__(256) void transpose_v_bf16(
    const ushort* __restrict__ in, ushort* __restrict__ out)
{
    int z = blockIdx.z;
    const ushort* ip = in + (size_t)z * TT * HEAD_DIM;
    ushort* op = out + (size_t)z * TT * HEAD_DIM;
    __shared__ ushort tile[32][33];
    int tx = threadIdx.x, ty = threadIdx.y;
    int d0 = blockIdx.x * 32;
    int t0 = blockIdx.y * 32;
#pragma unroll
    for (int i = 0; i < 32; i += 8)
        tile[ty + i][tx] = ip[(size_t)(t0 + ty + i) * HEAD_DIM + d0 + tx];
    __syncthreads();
#pragma unroll
    for (int i = 0; i < 32; i += 8)
        op[(size_t)(d0 + ty + i) * TT + t0 + tx] = tile[tx][ty + i];
}

// ============ m97-style 128x128 MFMA GEMM mainloop ==========================
__device__ inline void gemm128_mainloop(
    const ushort* __restrict__ A, const ushort* __restrict__ BT,
    int rowBase, int colBase, ushort* Al, ushort* Bl,
    f32x4 acc[4][4], int wave, int lane)
{
    const int K = D_MODEL;
    int lr = lane & 15, quad = lane >> 4;
    int lrow = lane >> 2;
    int kq = lane & 3;
    int mq = (wave >> 1) * 64, nq = (wave & 1) * 64;

    const ushort* gA0 = A + (size_t)(rowBase + wave * 32 + lrow) * K + kq * 8;
    const ushort* gA1 = gA0 + (size_t)16 * K;
    const ushort* gB0 = BT + (size_t)(colBase + wave * 32 + lrow) * K + kq * 8;
    const ushort* gB1 = gB0 + (size_t)16 * K;
    ushort* lA0 = Al + (wave * 32) * 32;
    ushort* lA1 = Al + (wave * 32 + 16) * 32;
    ushort* lB0 = Bl + (wave * 32) * 32;
    ushort* lB1 = Bl + (wave * 32 + 16) * 32;

    for (int kt = 0; kt < K / 32; ++kt) {
        __syncthreads();
        int ko = kt * 32;
        load_lds16(gA0 + ko, lA0);
        load_lds16(gA1 + ko, lA1);
        load_lds16(gB0 + ko, lB0);
        load_lds16(gB1 + ko, lB1);
        __syncthreads();
        bf16x8 af[4], bf[4];
#pragma unroll
        for (int mi = 0; mi < 4; ++mi)
            af[mi] = *(const bf16x8*)(Al + (mq + mi * 16 + lr) * 32 + quad * 8);
#pragma unroll
        for (int ni = 0; ni < 4; ++ni)
            bf[ni] = *(const bf16x8*)(Bl + (nq + ni * 16 + lr) * 32 + quad * 8);
#pragma unroll
        for (int mi = 0; mi < 4; ++mi)
#pragma unroll
            for (int ni = 0; ni < 4; ++ni)
                acc[mi][ni] = __builtin_amdgcn_mfma_f32_16x16x32_bf16(
                    af[mi], bf[ni], acc[mi][ni], 0, 0, 0);
    }
}

// QKV projection: qkv = xb @ Wqkv -> Q (pre-scaled), K, V all [bh][t][64] bf16.
__global__ __launch_bounds__(256) void gemm_qkv(
    const ushort* __restrict__ A, const ushort* __restrict__ BT,
    ushort* __restrict__ Qo, ushort* __restrict__ Ko, ushort* __restrict__ Vo)
{
    __shared__ ushort Al[128 * 32];
    __shared__ ushort Bl[128 * 32];
    int tid = threadIdx.x;
    int wave = tid >> 6, lane = tid & 63;
    int lr = lane & 15, quad = lane >> 4;
    int rowBase = blockIdx.y * 128;
    int colBase = blockIdx.x * 128;
    f32x4 acc[4][4] = {};
    gemm128_mainloop(A, BT, rowBase, colBase, Al, Bl, acc, wave, lane);

    int mq = (wave >> 1) * 64, nq = (wave & 1) * 64;
#pragma unroll
    for (int ni = 0; ni < 4; ++ni) {
        int n = colBase + nq + ni * 16 + lr;
        int s = n >> 10;
        int cc = n & 1023;
        int h = cc >> 6, d = cc & 63;
        ushort* dst = (s == 0) ? Qo : (s == 1 ? Ko : Vo);
        float scale = (s == 0) ? QSCALE : 1.0f;
#pragma unroll
        for (int mi = 0; mi < 4; ++mi) {
#pragma unroll
            for (int i = 0; i < 4; ++i) {
                int m = rowBase + mq + mi * 16 + quad * 4 + i;
                int b = m >> 11, t = m & 2047;
                int bh = b * N_HEADS + h;
                dst[((size_t)bh * TT + t) * HEAD_DIM + d] = f2bf(acc[mi][ni][i] * scale);
            }
        }
    }
}

// Out-proj GEMM, 128(M)x64(N) tiles -> 512 blocks (2/CU). FP32 out.
__global__ __launch_bounds__(256) void gemm_plain(
    const ushort* __restrict__ A, const ushort* __restrict__ BT,
    float* __restrict__ O, int N)
{
    const int K = D_MODEL;
    __shared__ ushort Al[128 * 32];
    __shared__ ushort Bl[64 * 32];
    int tid = threadIdx.x;
    int wave = tid >> 6, lane = tid & 63;
    int lr = lane & 15, quad = lane >> 4;
    int lrow = lane >> 2, kq = lane & 3;
    int rowBase = blockIdx.y * 128;
    int colBase = blockIdx.x * 64;
    int mq = (wave >> 1) * 64, nq = (wave & 1) * 32;

    const ushort* gA0 = A + (size_t)(rowBase + wave * 32 + lrow) * K + kq * 8;
    const ushort* gA1 = gA0 + (size_t)16 * K;
    const ushort* gB0 = BT + (size_t)(colBase + wave * 32 + lrow) * K + kq * 8;
    const ushort* gB1 = gB0 + (size_t)16 * K;
    ushort* lA0 = Al + (wave * 32) * 32;
    ushort* lA1 = Al + (wave * 32 + 16) * 32;
    ushort* lB0 = Bl + (wave * 32) * 32;
    ushort* lB1 = Bl + (wave * 32 + 16) * 32;

    f32x4 acc[4][2] = {};
    for (int kt = 0; kt < K / 32; ++kt) {
        __syncthreads();
        int ko = kt * 32;
        load_lds16(gA0 + ko, lA0);
        load_lds16(gA1 + ko, lA1);
        if (wave < 2) {
            load_lds16(gB0 + ko, lB0);
            load_lds16(gB1 + ko, lB1);
        }
        __syncthreads();
        bf16x8 af[4], bf[2];
#pragma unroll
        for (int mi = 0; mi < 4; ++mi)
            af[mi] = *(const bf16x8*)(Al + (mq + mi * 16 + lr) * 32 + quad * 8);
#pragma unroll
        for (int ni = 0; ni < 2; ++ni)
            bf[ni] = *(const bf16x8*)(Bl + (nq + ni * 16 + lr) * 32 + quad * 8);
#pragma unroll
        for (int mi = 0; mi < 4; ++mi)
#pragma unroll
            for (int ni = 0; ni < 2; ++ni)
                acc[mi][ni] = __builtin_amdgcn_mfma_f32_16x16x32_bf16(
                    af[mi], bf[ni], acc[mi][ni], 0, 0, 0);
    }

#pragma unroll
    for (int mi = 0; mi < 4; ++mi)
#pragma unroll
        for (int ni = 0; ni < 2; ++ni) {
            int n = colBase + nq + ni * 16 + lr;
#pragma unroll
            for (int i = 0; i < 4; ++i) {
                int m = rowBase + mq + mi * 16 + quad * 4 + i;
                O[(size_t)m * N + n] = acc[mi][ni][i];
            }
        }
}

// ---------------- MFMA flash attention v10b: 32x32 swapped-QK, in-reg softmax
// (unchanged resubmit: R5 GPUAcquisitionTimeout, R6 container failure --
// kernel never ran; audited for hang/fault vectors, none found)
// R4 diagnosis: LDS-pipe-bound (~26 LDS ops/wave/sub incl. 16 ds_write_b16
// P round-trip; 8 waves/CU x ~400cy = ~3.2k cy/iter = measured wall).
// v10 (guide SB/T12):
//  - 32x32x16 MFMA, SWAPPED QK: sc = mfma(K,Q) -> S^T, each lane holds a
//    full P-row slice (col=lane&31=q). P never touches LDS.
//  - P->PV A-frags via 8 bf16-pack + 4 v_permlane32_swap_b32 (VALU only).
//  - row sums from the SAME bf16-rounded P bits (numerator==denominator,
//    matching the old ones-MFMA exactness); halves combined via self-swap.
//  - kb/vb fragment reads shared by the wave's two query groups:
//    LDS ops/wave/sub = 8 x ds_read_b128, conflict-free contiguous.
//  - wave owns mirror pair of 32-row groups (a, 63-a): 65 sub-tiles/wave.
//  - mapping bh=(sl>>4)*8+xcd, u=sl&15 (R3/R4-proven) so CU partners
//    (bid, bid+256) share u -> equal iteration count & finish time;
//    bh%8==xcd keeps each head's K/V on one XCD (2MB < 4MB L2, R4-verified).
//  - dbuf prefetch + single __syncthreads per 64-key tile (R3-proven).
// LDS 32KB/block (2 blocks/CU). Staging layout identical to v5 (chunk-major
// K [dslot][key], V [kslot][dim]).
__global__ __launch_bounds__(128, 1) void attn_flash(
    const ushort* __restrict__ Q,   // [bh][t][64] bf16 (pre-scaled, log2 domain)
    const ushort* __restrict__ K,   // [bh][t][64] bf16
    const ushort* __restrict__ VT,  // [bh][64][t] bf16
    ushort* __restrict__ AO)        // [b*T+t][1024] bf16
{
    int bid = blockIdx.x;           // 0..511
    int xcd = bid & 7;
    int sl  = bid >> 3;             // 0..63
    int bh  = (sl >> 4) * 8 + xcd;  // bh%8 == xcd -> per-XCD K/V = 4bh = 2MB
    int u   = sl & 15;              // CU partner (bid+256) shares u
    int tid = threadIdx.x;
    int w    = tid >> 6;            // wave 0..1
    int lane = tid & 63;
    int l31 = lane & 31, hi = lane >> 5;

    int a  = u * 2 + w;             // 0..31
    int gs = a;                     // shallow 32-row group
    int gd = 63 - a;                // deep 32-row group
    int bt64 = 32 - u;              // block-uniform 64-key tile count

    const ushort* Qb = Q  + (size_t)bh * TT * HEAD_DIM;
    const ushort* Kb = K  + (size_t)bh * TT * HEAD_DIM;
    const ushort* Vb = VT + (size_t)bh * HEAD_DIM * TT;

    __shared__ ushort Kl[2][8 * 64 * 8];  // [buf][dslot][key] 16B slots, 2x8KB
    __shared__ ushort Vl[2][8 * 64 * 8];  // [buf][kslot][dim] 16B slots, 2x8KB

    // staging: wave w covers dslots/kslots w*4..w*4+3 (8 instrs/wave/tile)
    const ushort* gK[4];
    const ushort* gV[4];
#pragma unroll
    for (int t = 0; t < 4; ++t) {
        gK[t] = Kb + (size_t)lane * HEAD_DIM + (w * 4 + t) * 8;
        gV[t] = Vb + (size_t)lane * TT + (w * 4 + t) * 8;
    }

    // Q fragments (B-operand): qa[gi][si] = Q[rb+l31][si*16 + hi*8 .. +7]
    int rb[2] = { gs << 5, gd << 5 };
    bf16x8 qa[2][4];
#pragma unroll
    for (int gi = 0; gi < 2; ++gi)
#pragma unroll
        for (int si = 0; si < 4; ++si)
            qa[gi][si] = *(const bf16x8*)(Qb + (size_t)(rb[gi] + l31) * HEAD_DIM
                                             + si * 16 + hi * 8);

    f32x16 o[2][2];                 // [group][dim-half]: row=q (crow), col=dim
#pragma unroll
    for (int gi = 0; gi < 2; ++gi)
#pragma unroll
        for (int dh = 0; dh < 2; ++dh)
#pragma unroll
            for (int i = 0; i < 16; ++i) o[gi][dh][i] = 0.0f;
    float l[2] = { 0.0f, 0.0f };

    // prologue: stage tile 0 into buf 0
#pragma unroll
    for (int t = 0; t < 4; ++t) {
        load_lds16(gK[t], Kl[0] + (w * 4 + t) * 512);
        load_lds16(gV[t], Vl[0] + (w * 4 + t) * 512);
    }
    __syncthreads();

    for (int kt64 = 0; kt64 < bt64; ++kt64) {
        int cur = kt64 & 1;
        if (kt64 + 1 < bt64) {      // prefetch next tile into other buffer
            size_t koff = (size_t)(kt64 + 1) * 64;
#pragma unroll
            for (int t = 0; t < 4; ++t) {
                load_lds16(gK[t] + koff * HEAD_DIM, Kl[cur ^ 1] + (w * 4 + t) * 512);
                load_lds16(gV[t] + koff,            Vl[cur ^ 1] + (w * 4 + t) * 512);
            }
        }
        const ushort* Klc = Kl[cur];
        const ushort* Vlc = Vl[cur];

#pragma unroll
        for (int sub = 0; sub < 2; ++sub) {
            int kt32 = kt64 * 2 + sub;
            if (kt32 > gd) break;

            // K frags (A-operand): kb[si] = K[sub*32+l31][si*16 + hi*8 ..]
            bf16x8 kb[4];
#pragma unroll
            for (int si = 0; si < 4; ++si)
                kb[si] = *(const bf16x8*)&Klc[((si * 2 + hi) * 64 + sub * 32 + l31) * 8];
            // V frags (B-operand): vb[kh][dh] = V[sub*32+kh*16+hi*8..][dh*32+l31]
            bf16x8 vb[2][2];
#pragma unroll
            for (int kh = 0; kh < 2; ++kh)
#pragma unroll
                for (int dh = 0; dh < 2; ++dh)
                    vb[kh][dh] = *(const bf16x8*)&Vlc[((sub * 4 + kh * 2 + hi) * 64
                                     + dh * 32 + l31) * 8];

#pragma unroll
            for (int gi = 0; gi < 2; ++gi) {
                int g = (gi == 0) ? gs : gd;
                if (gi == 0 && kt32 > gs) continue;

                // S^T = K.Q : col=lane&31=q, row=key crow(r)=(r&3)+8*(r>>2)+4*hi
                f32x16 sc;
#pragma unroll
                for (int i = 0; i < 16; ++i) sc[i] = -MSTATIC;
#pragma unroll
                for (int si = 0; si < 4; ++si)
                    sc = __builtin_amdgcn_mfma_f32_32x32x16_bf16(
                        kb[si], qa[gi][si], sc, 0, 0, 0);

                if (kt32 == g) {    // causal mask on the diagonal sub-tile
#pragma unroll
                    for (int r = 0; r < 16; ++r) {
                        int krow = (r & 3) + 8 * (r >> 2) + 4 * hi;
                        if (krow > l31) sc[r] = -3e38f;
                    }
                }

                // P = exp2(S - 12), bf16-rounded in registers
                ushort bb[16];
#pragma unroll
                for (int r = 0; r < 16; ++r)
                    bb[r] = f2bf_hw(__builtin_amdgcn_exp2f(sc[r]));

                // row sum from the SAME bf16 bits (bf16->f32 exact via <<16)
                float pb[16];
#pragma unroll
                for (int r = 0; r < 16; ++r)
                    pb[r] = __builtin_bit_cast(float, (unsigned int)bb[r] << 16);
                float rs = (((pb[0] + pb[1]) + (pb[2] + pb[3]))
                          + ((pb[4] + pb[5]) + (pb[6] + pb[7])))
                         + (((pb[8] + pb[9]) + (pb[10] + pb[11]))
                          + ((pb[12] + pb[13]) + (pb[14] + pb[15])));
                unsigned int xu = __builtin_bit_cast(unsigned int, rs);
                unsigned int yu = xu;
                pl32swap(xu, yu);   // xu+yu = own + partner half, all lanes
                l[gi] += __builtin_bit_cast(float, xu)
                       + __builtin_bit_cast(float, yu);

                // pack P pairs: C[n] covers keys crow pairs of this half
                unsigned int C0 = (unsigned int)bb[0]  | ((unsigned int)bb[1]  << 16);
                unsigned int C1 = (unsigned int)bb[2]  | ((unsigned int)bb[3]  << 16);
                unsigned int C2 = (unsigned int)bb[4]  | ((unsigned int)bb[5]  << 16);
                unsigned int C3 = (unsigned int)bb[6]  | ((unsigned int)bb[7]  << 16);
                unsigned int C4 = (unsigned int)bb[8]  | ((unsigned int)bb[9]  << 16);
                unsigned int C5 = (unsigned int)bb[10] | ((unsigned int)bb[11] << 16);
                unsigned int C6 = (unsigned int)bb[12] | ((unsigned int)bb[13] << 16);
                unsigned int C7 = (unsigned int)bb[14] | ((unsigned int)bb[15] << 16);
                // A-frag assembly (guide T12): one swap fills two dwords
                unsigned int d00 = C0, d02 = C2; pl32swap(d00, d02);
                unsigned int d01 = C1, d03 = C3; pl32swap(d01, d03);
                unsigned int d10 = C4, d12 = C6; pl32swap(d10, d12);
                unsigned int d11 = C5, d13 = C7; pl32swap(d11, d13);
                u32x4 w0; w0.x = d00; w0.y = d01; w0.z = d02; w0.w = d03;
                u32x4 w1; w1.x = d10; w1.y = d11; w1.z = d12; w1.w = d13;
                bf16x8 pa0 = __builtin_bit_cast(bf16x8, w0);
                bf16x8 pa1 = __builtin_bit_cast(bf16x8, w1);

                // O += P.V  (2 key-halves x 2 dim-halves)
#pragma unroll
                for (int dh = 0; dh < 2; ++dh) {
                    o[gi][dh] = __builtin_amdgcn_mfma_f32_32x32x16_bf16(
                        pa0, vb[0][dh], o[gi][dh], 0, 0, 0);
                    o[gi][dh] = __builtin_amdgcn_mfma_f32_32x32x16_bf16(
                        pa1, vb[1][dh], o[gi][dh], 0, 0, 0);
                }
            }
        }
        // single barrier: drains prefetch (latency covered by compute) and
        // guarantees all reads of buf[cur] done before next overwrite.
        __syncthreads();
    }

    // epilogue: transpose l via LDS (q lives in lane; O has q in regs)
    float* lf = (float*)&Kl[0][0];  // 128 floats, safe after final barrier
    if (hi == 0) {
        lf[(w * 2 + 0) * 32 + l31] = l[0];
        lf[(w * 2 + 1) * 32 + l31] = l[1];
    }
    __syncthreads();

    int b = bh >> 4, h = bh & 15;
#pragma unroll
    for (int gi = 0; gi < 2; ++gi) {
        f32x4 rl[4];
#pragma unroll
        for (int r4 = 0; r4 < 4; ++r4) {
            f32x4 lv = *(const f32x4*)&lf[(w * 2 + gi) * 32 + r4 * 8 + hi * 4];
#pragma unroll
            for (int i = 0; i < 4; ++i) rl[r4][i] = 1.0f / lv[i];
        }
#pragma unroll
        for (int dh = 0; dh < 2; ++dh)
#pragma unroll
            for (int r = 0; r < 16; ++r) {
                int row = rb[gi] + (r & 3) + 8 * (r >> 2) + 4 * hi;
                AO[((size_t)(b * TT + row)) * D_MODEL + h * HEAD_DIM + dh * 32 + l31] =
                    f2bf(o[gi][dh][r] * rl[r >> 2][r & 3]);
            }
    }
}

// ---------------------------------------------------------------------------
extern "C" void kernel_launch(void* const* d_in, const int* in_sizes, int n_in,
                              void* d_out, int out_size, void* d_ws, size_t ws_size,
                              hipStream_t stream)
{
    (void)in_sizes; (void)n_in; (void)out_size; (void)ws_size;
    const float* x    = (const float*)d_in[0];   // [B*T, C] fp32
    const float* Wqkv = (const float*)d_in[1];   // [C, 3C] fp32
    const float* Wo   = (const float*)d_in[2];   // [C, C]  fp32
    float* out = (float*)d_out;                  // [B*T, C] fp32

    char* ws = (char*)d_ws;
    size_t off = 0;
    ushort* WqkvT = (ushort*)(ws + off); off += (size_t)3 * D_MODEL * D_MODEL * 2;
    ushort* WoT   = (ushort*)(ws + off); off += (size_t)D_MODEL * D_MODEL * 2;
    ushort* xb    = (ushort*)(ws + off); off += (size_t)BB * TT * D_MODEL * 2;
    ushort* Qd    = (ushort*)(ws + off); off += (size_t)BB * D_MODEL * TT * 2;
    ushort* Kd    = (ushort*)(ws + off); off += (size_t)BB * D_MODEL * TT * 2;
    ushort* Vd    = (ushort*)(ws + off); off += (size_t)BB * D_MODEL * TT * 2;
    ushort* VTd   = (ushort*)(ws + off); off += (size_t)BB * D_MODEL * TT * 2;
    ushort* AO    = (ushort*)(ws + off); off += (size_t)BB * TT * D_MODEL * 2;

    // fused prep: x->bf16 + both weight transposes
    prep<<<dim3(8192), 256, 0, stream>>>(
        (const float4*)x, (ushort4*)xb, Wqkv, WqkvT, Wo, WoT);

    // qkv = xb @ Wqkv -> bf16 Q (pre-scaled), K, V all [bh][t][64]
    gemm_qkv<<<dim3(3 * D_MODEL / 128, BB * TT / 128), 256, 0, stream>>>(
        xb, WqkvT, Qd, Kd, Vd);

    // V -> V^T per head
    transpose_v_bf16<<<dim3(HEAD_DIM / 32, TT / 32, BB * N_HEADS), dim3(32, 8), 0, stream>>>(
        Vd, VTd);

    // MFMA flash attention (32x32 swapped-QK, in-register softmax)
    attn_flash<<<dim3(512), 128, 0, stream>>>(Qd, Kd, VTd, AO);

    // out = AO @ Wo (fp32 out)
    gemm_plain<<<dim3(D_MODEL / 64, BB * TT / 128), 256, 0, stream>>>(
        AO, WoT, out, D_MODEL);
}

// Round 11
// 193.570 us; speedup vs baseline: 1.0951x; 1.0951x over previous
//
#include <hip/hip_runtime.h>
#include <cstdint>
#include <math.h>

// Problem constants
#define D_MODEL 1024
#define N_HEADS 16
#define HEAD_DIM 64
#define BB 2
#define TT 2048
// Inputs fp32, OUTPUT fp32. Internal: bf16 MFMA GEMMs + bf16 MFMA flash attention.
// Q pre-scaled by (1/32)*log2(e) so softmax uses exp2 (v_exp_f32).
#define QSCALE 0.04508422002778011f
// Static softmax shift (R6): logits tiny; shift folded into QK acc init.
#define MSTATIC 12.0f

typedef float f32x4 __attribute__((ext_vector_type(4)));
typedef __bf16 bf16x8 __attribute__((ext_vector_type(8)));

__device__ inline ushort f2bf(float f) {
    union { float f; uint32_t u; } c; c.f = f;
    uint32_t u = c.u;
    uint32_t r = (u + 0x7FFFu + ((u >> 16) & 1u)) >> 16;  // RNE
    return (ushort)r;
}
__device__ inline ushort f2bf_hw(float f) {
    __bf16 h = (__bf16)f;
    return __builtin_bit_cast(ushort, h);
}

// async global->LDS, 16B per lane; LDS dest = uniform base + lane*16B (m97/m104)
__device__ inline void load_lds16(const ushort* g, ushort* lds_uniform_base) {
    __builtin_amdgcn_global_load_lds(
        (const __attribute__((address_space(1))) uint32_t*)g,
        (__attribute__((address_space(3))) uint32_t*)lds_uniform_base, 16, 0, 0);
}

// ---------------- fused prep: conv_x + Wqkv^T + Wo^T (one launch) ----------
__global__ __launch_bounds__(256) void prep(
    const float4* __restrict__ xin, ushort4* __restrict__ xb,
    const float* __restrict__ Wqkv, ushort* __restrict__ WqkvT,
    const float* __restrict__ Wo, ushort* __restrict__ WoT)
{
    int bid = blockIdx.x;
    int tid = threadIdx.x;
    if (bid < 4096) {
        int i = bid * 256 + tid;
        float4 v = xin[i];
        ushort4 u;
        u.x = f2bf(v.x); u.y = f2bf(v.y); u.z = f2bf(v.z); u.w = f2bf(v.w);
        xb[i] = u;
        return;
    }
    __shared__ ushort tile[32][33];
    int tx = tid & 31, ty = tid >> 5;
    const float* in; ushort* out; int R, C, c0, r0;
    if (bid < 7168) {
        int b2 = bid - 4096;
        in = Wqkv; out = WqkvT; R = D_MODEL; C = 3 * D_MODEL;
        c0 = (b2 % 96) * 32; r0 = (b2 / 96) * 32;
    } else {
        int b3 = bid - 7168;
        in = Wo; out = WoT; R = D_MODEL; C = D_MODEL;
        c0 = (b3 % 32) * 32; r0 = (b3 / 32) * 32;
    }
#pragma unroll
    for (int i = 0; i < 32; i += 8)
        tile[ty + i][tx] = f2bf(in[(size_t)(r0 + ty + i) * C + (c0 + tx)]);
    __syncthreads();
#pragma unroll
    for (int i = 0; i < 32; i += 8)
        out[(size_t)(c0 + ty + i) * R + (r0 + tx)] = tile[tx][ty + i];
}

// --------- V [bh][t][64] bf16 -> VT [bh][64][t] bf16 ------------------------
__global__ __launch_bounds__(256) void transpose_v_bf16(
    const ushort* __restrict__ in, ushort* __restrict__ out)
{
    int z = blockIdx.z;
    const ushort* ip = in + (size_t)z * TT * HEAD_DIM;
    ushort* op = out + (size_t)z * TT * HEAD_DIM;
    __shared__ ushort tile[32][33];
    int tx = threadIdx.x, ty = threadIdx.y;
    int d0 = blockIdx.x * 32;
    int t0 = blockIdx.y * 32;
#pragma unroll
    for (int i = 0; i < 32; i += 8)
        tile[ty + i][tx] = ip[(size_t)(t0 + ty + i) * HEAD_DIM + d0 + tx];
    __syncthreads();
#pragma unroll
    for (int i = 0; i < 32; i += 8)
        op[(size_t)(d0 + ty + i) * TT + t0 + tx] = tile[tx][ty + i];
}

// ============ m97-style 128x128 MFMA GEMM mainloop ==========================
__device__ inline void gemm128_mainloop(
    const ushort* __restrict__ A, const ushort* __restrict__ BT,
    int rowBase, int colBase, ushort* Al, ushort* Bl,
    f32x4 acc[4][4], int wave, int lane)
{
    const int K = D_MODEL;
    int lr = lane & 15, quad = lane >> 4;
    int lrow = lane >> 2;
    int kq = lane & 3;
    int mq = (wave >> 1) * 64, nq = (wave & 1) * 64;

    const ushort* gA0 = A + (size_t)(rowBase + wave * 32 + lrow) * K + kq * 8;
    const ushort* gA1 = gA0 + (size_t)16 * K;
    const ushort* gB0 = BT + (size_t)(colBase + wave * 32 + lrow) * K + kq * 8;
    const ushort* gB1 = gB0 + (size_t)16 * K;
    ushort* lA0 = Al + (wave * 32) * 32;
    ushort* lA1 = Al + (wave * 32 + 16) * 32;
    ushort* lB0 = Bl + (wave * 32) * 32;
    ushort* lB1 = Bl + (wave * 32 + 16) * 32;

    for (int kt = 0; kt < K / 32; ++kt) {
        __syncthreads();
        int ko = kt * 32;
        load_lds16(gA0 + ko, lA0);
        load_lds16(gA1 + ko, lA1);
        load_lds16(gB0 + ko, lB0);
        load_lds16(gB1 + ko, lB1);
        __syncthreads();
        bf16x8 af[4], bf[4];
#pragma unroll
        for (int mi = 0; mi < 4; ++mi)
            af[mi] = *(const bf16x8*)(Al + (mq + mi * 16 + lr) * 32 + quad * 8);
#pragma unroll
        for (int ni = 0; ni < 4; ++ni)
            bf[ni] = *(const bf16x8*)(Bl + (nq + ni * 16 + lr) * 32 + quad * 8);
#pragma unroll
        for (int mi = 0; mi < 4; ++mi)
#pragma unroll
            for (int ni = 0; ni < 4; ++ni)
                acc[mi][ni] = __builtin_amdgcn_mfma_f32_16x16x32_bf16(
                    af[mi], bf[ni], acc[mi][ni], 0, 0, 0);
    }
}

// QKV projection: qkv = xb @ Wqkv -> Q (pre-scaled), K, V all [bh][t][64] bf16.
__global__ __launch_bounds__(256) void gemm_qkv(
    const ushort* __restrict__ A, const ushort* __restrict__ BT,
    ushort* __restrict__ Qo, ushort* __restrict__ Ko, ushort* __restrict__ Vo)
{
    __shared__ ushort Al[128 * 32];
    __shared__ ushort Bl[128 * 32];
    int tid = threadIdx.x;
    int wave = tid >> 6, lane = tid & 63;
    int lr = lane & 15, quad = lane >> 4;
    int rowBase = blockIdx.y * 128;
    int colBase = blockIdx.x * 128;
    f32x4 acc[4][4] = {};
    gemm128_mainloop(A, BT, rowBase, colBase, Al, Bl, acc, wave, lane);

    int mq = (wave >> 1) * 64, nq = (wave & 1) * 64;
#pragma unroll
    for (int ni = 0; ni < 4; ++ni) {
        int n = colBase + nq + ni * 16 + lr;
        int s = n >> 10;
        int cc = n & 1023;
        int h = cc >> 6, d = cc & 63;
        ushort* dst = (s == 0) ? Qo : (s == 1 ? Ko : Vo);
        float scale = (s == 0) ? QSCALE : 1.0f;
#pragma unroll
        for (int mi = 0; mi < 4; ++mi) {
#pragma unroll
            for (int i = 0; i < 4; ++i) {
                int m = rowBase + mq + mi * 16 + quad * 4 + i;
                int b = m >> 11, t = m & 2047;
                int bh = b * N_HEADS + h;
                dst[((size_t)bh * TT + t) * HEAD_DIM + d] = f2bf(acc[mi][ni][i] * scale);
            }
        }
    }
}

// Out-proj GEMM, 128(M)x64(N) tiles -> 512 blocks (2/CU). FP32 out.
__global__ __launch_bounds__(256) void gemm_plain(
    const ushort* __restrict__ A, const ushort* __restrict__ BT,
    float* __restrict__ O, int N)
{
    const int K = D_MODEL;
    __shared__ ushort Al[128 * 32];
    __shared__ ushort Bl[64 * 32];
    int tid = threadIdx.x;
    int wave = tid >> 6, lane = tid & 63;
    int lr = lane & 15, quad = lane >> 4;
    int lrow = lane >> 2, kq = lane & 3;
    int rowBase = blockIdx.y * 128;
    int colBase = blockIdx.x * 64;
    int mq = (wave >> 1) * 64, nq = (wave & 1) * 32;

    const ushort* gA0 = A + (size_t)(rowBase + wave * 32 + lrow) * K + kq * 8;
    const ushort* gA1 = gA0 + (size_t)16 * K;
    const ushort* gB0 = BT + (size_t)(colBase + wave * 32 + lrow) * K + kq * 8;
    const ushort* gB1 = gB0 + (size_t)16 * K;
    ushort* lA0 = Al + (wave * 32) * 32;
    ushort* lA1 = Al + (wave * 32 + 16) * 32;
    ushort* lB0 = Bl + (wave * 32) * 32;
    ushort* lB1 = Bl + (wave * 32 + 16) * 32;

    f32x4 acc[4][2] = {};
    for (int kt = 0; kt < K / 32; ++kt) {
        __syncthreads();
        int ko = kt * 32;
        load_lds16(gA0 + ko, lA0);
        load_lds16(gA1 + ko, lA1);
        if (wave < 2) {
            load_lds16(gB0 + ko, lB0);
            load_lds16(gB1 + ko, lB1);
        }
        __syncthreads();
        bf16x8 af[4], bf[2];
#pragma unroll
        for (int mi = 0; mi < 4; ++mi)
            af[mi] = *(const bf16x8*)(Al + (mq + mi * 16 + lr) * 32 + quad * 8);
#pragma unroll
        for (int ni = 0; ni < 2; ++ni)
            bf[ni] = *(const bf16x8*)(Bl + (nq + ni * 16 + lr) * 32 + quad * 8);
#pragma unroll
        for (int mi = 0; mi < 4; ++mi)
#pragma unroll
            for (int ni = 0; ni < 2; ++ni)
                acc[mi][ni] = __builtin_amdgcn_mfma_f32_16x16x32_bf16(
                    af[mi], bf[ni], acc[mi][ni], 0, 0, 0);
    }

#pragma unroll
    for (int mi = 0; mi < 4; ++mi)
#pragma unroll
        for (int ni = 0; ni < 2; ++ni) {
            int n = colBase + nq + ni * 16 + lr;
#pragma unroll
            for (int i = 0; i < 4; ++i) {
                int m = rowBase + mq + mi * 16 + quad * 4 + i;
                O[(size_t)m * N + n] = acc[mi][ni][i];
            }
        }
}

// ---------------- MFMA flash attention v9: XCD-local K/V (T1) --------------
// v8 + XCD-aware block remap. Previously blocks sharing a bh (bid=bh*16+idx)
// landed on XCDs via bid%8 = idx%8 -> every bh's 512KB K/V streamed through
// ALL 8 XCD L2s (per-XCD working set 16MB >> 4MB L2) -> 62.5MB HBM fetch
// (4x compulsory) and ~900cy miss latency that 1-tile prefetch can't cover.
// Remap: xcd = bid&7, slot = bid>>3, bh = (slot>>4)*8 + xcd, idx = slot&15.
// All 16 blocks of a bh share an XCD (bh%8==xcd); per-XCD unique K/V =
// 4 bh x 512KB = 2MB < 4MB L2 -> K/V tile loads become L2 hits (~200cy),
// hidden by the existing prefetch. Bijective; CU-partner (bid+256) keeps
// the same idx -> v7's balance property preserved. Perf-only: correctness
// does not depend on the actual XCD assignment.
// [R10 note: reverted to this exact R4-verified kernel after the 32x32
//  restructure line (v10-v12) failed correctness 3x. Best known good.]
__global__ __launch_bounds__(256) void attn_flash(
    const ushort* __restrict__ Q,   // [bh][t][64] bf16 (pre-scaled, log2 domain)
    const ushort* __restrict__ K,   // [bh][t][64] bf16
    const ushort* __restrict__ VT,  // [bh][64][t] bf16
    ushort* __restrict__ AO)        // [b*T+t][1024] bf16
{
    int bid = blockIdx.x;           // 0..511
    int xcd  = bid & 7;
    int slot = bid >> 3;            // 0..63
    int bh   = (slot >> 4) * 8 + xcd;   // 0..31, constant-XCD per bh
    int idx  = slot & 15;           // 0..15
    int tid = threadIdx.x;
    int wave = tid >> 6, lane = tid & 63;
    int quad = lane >> 4, lr = lane & 15;

    int a    = idx * 4 + wave;      // light 16-row group, 0..63
    int Gl   = a;                   // shallow fragment group
    int Gh   = 127 - a;             // deep fragment group, 64..127
    int rowl = Gl << 4;
    int rowh = Gh << 4;
    int liml = Gl >> 1;             // last active 32-key sub-tile (shallow)
    int limh = Gh >> 1;             // last active 32-key sub-tile (deep)
    int bt64 = 32 - idx;            // block-uniform 64-tile count

    const ushort* Qb = Q  + (size_t)bh * TT * HEAD_DIM;
    const ushort* Kb = K  + (size_t)bh * TT * HEAD_DIM;
    const ushort* Vb = VT + (size_t)bh * HEAD_DIM * TT;

    __shared__ ushort Kl[2][8 * 64 * 8];  // [buf][chunk][key] 16B slots, 2x8KB
    __shared__ ushort Vl[2][8 * 64 * 8];  // [buf][sub*4+kc][dim] 16B slots, 2x8KB
    __shared__ ushort pbuf[4][32][40];    // per-wave P, stride 40 (4-way writes)
    ushort (*P)[40] = pbuf[wave];

    // staging: wave w handles K-instrs t=w,w+4 and V-instrs t=w,w+4.
    const ushort* gK0 = Kb + (size_t)lane * HEAD_DIM + wave * 8;
    const ushort* gK1 = Kb + (size_t)lane * HEAD_DIM + (wave + 4) * 8;
    const ushort* gV0 = Vb + (size_t)lane * TT + wave * 8;           // sub 0
    const ushort* gV1 = Vb + (size_t)lane * TT + 32 + wave * 8;      // sub 1

    bf16x8 qa[2][2];
#pragma unroll
    for (int r = 0; r < 2; ++r) {
        int rb = (r == 0) ? rowl : rowh;
#pragma unroll
        for (int s = 0; s < 2; ++s)
            qa[r][s] = *(const bf16x8*)(Qb + (size_t)(rb + lr) * HEAD_DIM
                                           + s * 32 + quad * 8);
    }

    f32x4 o[2][4] = {};
    f32x4 l[2] = {};

    bf16x8 ones;
#pragma unroll
    for (int j = 0; j < 8; ++j) ones[j] = (__bf16)1.0f;

    // prologue: stage tile 0 into buf 0
    load_lds16(gK0, Kl[0] + wave * 512);
    load_lds16(gK1, Kl[0] + (wave + 4) * 512);
    load_lds16(gV0, Vl[0] + wave * 512);
    load_lds16(gV1, Vl[0] + (wave + 4) * 512);
    __syncthreads();                     // tile 0 ready

    for (int kt64 = 0; kt64 < bt64; ++kt64) {
        int cur = kt64 & 1;
        // issue NEXT tile's loads first -- latency hides under compute below
        if (kt64 + 1 < bt64) {
            size_t koff = (size_t)(kt64 + 1) * 64;
            ushort* KlN = Kl[cur ^ 1];
            ushort* VlN = Vl[cur ^ 1];
            load_lds16(gK0 + koff * HEAD_DIM, KlN + wave * 512);
            load_lds16(gK1 + koff * HEAD_DIM, KlN + (wave + 4) * 512);
            load_lds16(gV0 + koff, VlN + wave * 512);
            load_lds16(gV1 + koff, VlN + (wave + 4) * 512);
        }
        const ushort* Klc = Kl[cur];
        const ushort* Vlc = Vl[cur];

#pragma unroll
        for (int sub = 0; sub < 2; ++sub) {
            int kt32 = kt64 * 2 + sub;
            if (kt32 > limh) break;      // wave idle (rare: last sub only)
            int act0 = (kt32 <= liml);

            // K fragments: B[k=dim s*32+quad*8+j][n=key c*16+lr]
            bf16x8 kb[2][2];
#pragma unroll
            for (int c = 0; c < 2; ++c)
#pragma unroll
                for (int s = 0; s < 2; ++s)
                    kb[c][s] = *(const bf16x8*)&Klc[(((s * 4 + quad) * 64)
                                 + sub * 32 + c * 16 + lr) * 8];
            // V fragments: B[k=key quad*8+j][n=dim d*16+lr]
            bf16x8 vb[4];
#pragma unroll
            for (int d = 0; d < 4; ++d)
                vb[d] = *(const bf16x8*)&Vlc[(((sub * 4 + quad) * 64)
                             + d * 16 + lr) * 8];

#pragma unroll
            for (int r = 0; r < 2; ++r) {
                if (r == 0 && !act0) continue;
                int rb  = (r == 0) ? rowl : rowh;
                int lim = (r == 0) ? liml : limh;

                // S - MSTATIC via accumulator init
                f32x4 sc[2];
#pragma unroll
                for (int c = 0; c < 2; ++c)
#pragma unroll
                    for (int i = 0; i < 4; ++i) sc[c][i] = -MSTATIC;
#pragma unroll
                for (int c = 0; c < 2; ++c) {
                    sc[c] = __builtin_amdgcn_mfma_f32_16x16x32_bf16(qa[r][0], kb[c][0], sc[c], 0, 0, 0);
                    sc[c] = __builtin_amdgcn_mfma_f32_16x16x32_bf16(qa[r][1], kb[c][1], sc[c], 0, 0, 0);
                }
                // causal mask on this fragment's diagonal sub-tile
                if (kt32 == lim) {
#pragma unroll
                    for (int c = 0; c < 2; ++c)
#pragma unroll
                        for (int i = 0; i < 4; ++i)
                            if (kt32 * 32 + c * 16 + lr > rb + quad * 4 + i)
                                sc[c][i] = -3e38f;
                }
                // P = exp2(S - 12) -> LDS bf16
#pragma unroll
                for (int c = 0; c < 2; ++c)
#pragma unroll
                    for (int i = 0; i < 4; ++i)
                        P[r * 16 + quad * 4 + i][c * 16 + lr] =
                            f2bf_hw(__builtin_amdgcn_exp2f(sc[c][i]));
            }

            // PV (+ row sums via ones-MFMA => l matches bf16 P exactly)
#pragma unroll
            for (int r = 0; r < 2; ++r) {
                if (r == 0 && !act0) continue;
                bf16x8 pa = *(const bf16x8*)&P[r * 16 + lr][quad * 8];
                l[r] = __builtin_amdgcn_mfma_f32_16x16x32_bf16(pa, ones, l[r], 0, 0, 0);
#pragma unroll
                for (int d = 0; d < 4; ++d)
                    o[r][d] = __builtin_amdgcn_mfma_f32_16x16x32_bf16(pa, vb[d], o[r][d], 0, 0, 0);
            }
        }
        // single barrier: (a) drains vmcnt(0) -> tile kt64+1 ready (latency
        // already covered by the compute above); (b) all waves' ds_reads of
        // buf[cur] done -> safe to overwrite next iteration.
        __syncthreads();
    }

    // epilogue: AO[b*T + row][h*64 + dim] = O / l   (both fragments)
    int b = bh >> 4, h = bh & 15;
#pragma unroll
    for (int r = 0; r < 2; ++r) {
        int rb = (r == 0) ? rowl : rowh;
        f32x4 rl;
#pragma unroll
        for (int i = 0; i < 4; ++i) rl[i] = 1.0f / l[r][i];
#pragma unroll
        for (int d = 0; d < 4; ++d)
#pragma unroll
            for (int i = 0; i < 4; ++i) {
                int row = rb + quad * 4 + i;
                AO[((size_t)(b * TT + row)) * D_MODEL + h * HEAD_DIM + d * 16 + lr] =
                    f2bf(o[r][d][i] * rl[i]);
            }
    }
}

// ---------------------------------------------------------------------------
extern "C" void kernel_launch(void* const* d_in, const int* in_sizes, int n_in,
                              void* d_out, int out_size, void* d_ws, size_t ws_size,
                              hipStream_t stream)
{
    (void)in_sizes; (void)n_in; (void)out_size; (void)ws_size;
    const float* x    = (const float*)d_in[0];   // [B*T, C] fp32
    const float* Wqkv = (const float*)d_in[1];   // [C, 3C] fp32
    const float* Wo   = (const float*)d_in[2];   // [C, C]  fp32
    float* out = (float*)d_out;                  // [B*T, C] fp32

    char* ws = (char*)d_ws;
    size_t off = 0;
    ushort* WqkvT = (ushort*)(ws + off); off += (size_t)3 * D_MODEL * D_MODEL * 2;
    ushort* WoT   = (ushort*)(ws + off); off += (size_t)D_MODEL * D_MODEL * 2;
    ushort* xb    = (ushort*)(ws + off); off += (size_t)BB * TT * D_MODEL * 2;
    ushort* Qd    = (ushort*)(ws + off); off += (size_t)BB * D_MODEL * TT * 2;
    ushort* Kd    = (ushort*)(ws + off); off += (size_t)BB * D_MODEL * TT * 2;
    ushort* Vd    = (ushort*)(ws + off); off += (size_t)BB * D_MODEL * TT * 2;
    ushort* VTd   = (ushort*)(ws + off); off += (size_t)BB * D_MODEL * TT * 2;
    ushort* AO    = (ushort*)(ws + off); off += (size_t)BB * TT * D_MODEL * 2;

    // fused prep: x->bf16 + both weight transposes
    prep<<<dim3(8192), 256, 0, stream>>>(
        (const float4*)x, (ushort4*)xb, Wqkv, WqkvT, Wo, WoT);

    // qkv = xb @ Wqkv -> bf16 Q (pre-scaled), K, V all [bh][t][64]
    gemm_qkv<<<dim3(3 * D_MODEL / 128, BB * TT / 128), 256, 0, stream>>>(
        xb, WqkvT, Qd, Kd, Vd);

    // V -> V^T per head
    transpose_v_bf16<<<dim3(HEAD_DIM / 32, TT / 32, BB * N_HEADS), dim3(32, 8), 0, stream>>>(
        Vd, VTd);

    // MFMA flash attention (mirror-pair balanced + prefetch + XCD-local K/V)
    attn_flash<<<dim3(512), 256, 0, stream>>>(Qd, Kd, VTd, AO);

    // out = AO @ Wo (fp32 out)
    gemm_plain<<<dim3(D_MODEL / 64, BB * TT / 128), 256, 0, stream>>>(
        AO, WoT, out, D_MODEL);
}